// Round 11
// baseline (181.484 us; speedup 1.0000x reference)
//
#include <hip/hip_runtime.h>
#include <hip/hip_bf16.h>

// B=16, S=2048, D=128 causal attention, pre-scale threshold:
//   A = Q@T^T; A = (A>0.3 ? A : 0); causal -2^32; /sqrt(128); softmax; @V
// fp32 in/out, bf16 MFMA internal. Fixed-max softmax (m=0; post-threshold
// logits in [0,~9]) => partial (oacc, sum-l) accumulators are ADDITIVE.
//
// V11 = V7 (best verified: fa 44us, 104 VGPR, 4-wave, key-split QK^T /
// d-split PV, shared-P, dbuf tiles) + three surgical deltas:
//  1. 2 barriers/slot (was 3): issueTile(s+1) moved AFTER b1. b1(s) proves
//     all waves finished slot s-1 (program order), so overwriting buf
//     (s+1)&1 after b1(s) is safe -- b3 deleted. vmcnt(0) at slot top waits
//     only tile-s loads (s+1 not yet issued); DMA in-flight window = the
//     full compute phase of the previous slot (>= 2K cyc > ~900 HBM lat).
//  2. nrm kernel folded into fa (saves a ~13us launch): chunks rebalanced
//     c0 = light(L) + heavy prefix(16-L) = 16 slots, c1 = heavy suffix 17
//     slots incl. diagonal => c1 naturally arrives last; spin ~free.
//     V5/V9-proven release/acquire protocol; all 512 blocks co-resident at
//     2 blocks/CU (73728B LDS). bf16 partials (proven V5/V9/V10).
//  3. exp2f(s*EXP2C) -- one v_mul + v_exp per element.
// Known-bad regimes avoided (measured): 8-wave lockstep blocks (V2/V8/V9),
// launch-bounds VGPR caps <=128 (V3/V6 spills), single-buffer tiles (V10).

#define S_LEN 2048
#define D_DIM 128
#define THRESH 0.3f
#define EXP2C 0.12751742f   // (1/sqrt(128)) * log2(e)

typedef __bf16 bf16x8 __attribute__((ext_vector_type(8)));
typedef __bf16 bf16x4 __attribute__((ext_vector_type(4)));
typedef float f32x4 __attribute__((ext_vector_type(4)));

#define GLD16(g, l)                                                         \
    __builtin_amdgcn_global_load_lds(                                       \
        (const __attribute__((address_space(1))) unsigned int*)(g),         \
        (__attribute__((address_space(3))) unsigned int*)(l), 16, 0, 0)

// ---- prep: Tb bf16 downcast; Vt[b][d][s] bf16 transpose; zero done ctrs ----
__global__ void prep_kernel(const float* __restrict__ V, const float* __restrict__ T,
                            __bf16* __restrict__ Vt, __bf16* __restrict__ Tb,
                            int* __restrict__ done) {
    __shared__ float tile[64][65];
    int bid = blockIdx.x;                      // 1024 blocks
    int tid = threadIdx.x;                     // 256 threads
    if (bid == 0) done[tid] = 0;               // zero 256 counters
    int b  = bid >> 6;
    int t2 = bid & 63;

    {   // T downcast: rows [t2*32, t2*32+32) of batch b; 16 f32 per thread
        int flat = tid * 16;
        int r = flat >> 7, cc = flat & 127;
        const float* p = T + ((size_t)b * S_LEN + t2 * 32 + r) * D_DIM + cc;
        __bf16* q = Tb + ((size_t)b * S_LEN + t2 * 32 + r) * D_DIM + cc;
        bf16x8 w0, w1;
        f32x4 a0 = *(const f32x4*)p,       a1 = *(const f32x4*)(p + 4);
        f32x4 a2 = *(const f32x4*)(p + 8), a3 = *(const f32x4*)(p + 12);
        #pragma unroll
        for (int j = 0; j < 4; ++j) {
            w0[j] = (__bf16)a0[j]; w0[4 + j] = (__bf16)a1[j];
            w1[j] = (__bf16)a2[j]; w1[4 + j] = (__bf16)a3[j];
        }
        *(bf16x8*)q = w0;
        *(bf16x8*)(q + 8) = w1;
    }

    int s0 = (t2 >> 1) * 64;
    int d0 = (t2 & 1) * 64;
    #pragma unroll
    for (int it = 0; it < 2; ++it) {
        int row = it * 32 + (tid >> 3);
        int c   = (tid & 7) * 8;
        const float* p = V + ((size_t)b * S_LEN + s0 + row) * D_DIM + d0 + c;
        *(f32x4*)(&tile[row][c])     = *(const f32x4*)p;
        *(f32x4*)(&tile[row][c + 4]) = *(const f32x4*)(p + 4);
    }
    __syncthreads();
    #pragma unroll
    for (int it = 0; it < 2; ++it) {
        int dr = it * 32 + (tid >> 3);
        int c  = (tid & 7) * 8;
        bf16x8 w;
        #pragma unroll
        for (int j = 0; j < 8; ++j) w[j] = (__bf16)tile[c + j][dr];
        *(bf16x8*)(Vt + ((size_t)b * D_DIM + d0 + dr) * S_LEN + s0 + c) = w;
    }
}

// ---------------- Flash attention, causal + threshold, fixed-max ----------------
// 256 threads = 4 waves. LDS 73728 B => 2 blocks/CU:
//   [    0, 32768)  Tt dbuf: 2 x (64 rows x 256B), XOR-swizzled via DMA source
//   [32768, 65536)  Vl dbuf: 2 x (128 rows x 128B), XOR-swizzled via DMA source
//   [65536, 73728)  P: shared [64 q][128B keys] swizzled; first 1KB doubles as
//                   Lx[4][64] cross-wave l-reduction buffer between segments.
__global__ __launch_bounds__(256, 2)
void fa_kernel(const float* __restrict__ Q, const __bf16* __restrict__ Tb,
               const __bf16* __restrict__ Vt, float* __restrict__ O,
               __bf16* __restrict__ pO, float* __restrict__ pL,
               int* __restrict__ done) {
    __shared__ __align__(16) unsigned char smem[73728];

    const int bid = blockIdx.x;          // 512: b fastest (XCD L2 locality)
    const int b   = bid & 15;
    const int pi  = (bid >> 4) & 15;     // pair index: q-tiles (pi, 31-pi)
    const int c   = bid >> 8;            // chunk 0/1
    const int qtH = 31 - pi;
    const int L   = pi + 1;              // light tile count (1..16)
    const int pr  = b * 16 + pi;         // pair id 0..255

    const int tid  = threadIdx.x;
    const int lane = tid & 63;
    const int wv   = tid >> 6;
    const int col  = lane & 15;
    const int quad = lane >> 4;

    unsigned char* Pb = smem + 65536;
    float* Lxf = (float*)(smem + 65536);

    const __bf16* TbB = Tb + (size_t)b * (S_LEN * D_DIM);
    const __bf16* VtB = Vt + (size_t)b * (D_DIM * S_LEN);

    // per-thread pre-swizzled global source offsets for the 4+4 DMA issues
    int toff[4], voff[4];
    #pragma unroll
    for (int i = 0; i < 4; ++i) {
        int trw = wv * 16 + i * 4 + (lane >> 4);
        toff[i] = trw * 128 + (((lane & 15) ^ (trw & 7)) << 3);
        int drw = wv * 32 + i * 8 + (lane >> 3);
        voff[i] = drw * 2048 + (((lane & 7) ^ (drw & 7)) << 3);
    }

    auto issueTile = [&](int k0, int buf) {
        const __bf16* ts = TbB + (size_t)k0 * D_DIM;
        const __bf16* vs = VtB + k0;
        unsigned char* lt = smem + buf * 16384 + wv * 4096;
        unsigned char* lv = smem + 32768 + buf * 16384 + wv * 4096;
        #pragma unroll
        for (int i = 0; i < 4; ++i) GLD16(ts + toff[i], lt + i * 1024);
        #pragma unroll
        for (int i = 0; i < 4; ++i) GLD16(vs + voff[i], lv + i * 1024);
    };

    // Q as PERSISTENT B-frags for all 64 q-rows: qf[t][kk] holds
    // Q[q = 16t+col][k = kk*32 + quad*8 + j]   (64 VGPRs)
    bf16x8 qf[4][4];
    auto loadQ = [&](int jq) {
        #pragma unroll
        for (int t = 0; t < 4; ++t) {
            const float* qptr = Q + ((size_t)b * S_LEN + jq * 64 + 16 * t + col) * D_DIM + quad * 8;
            #pragma unroll
            for (int kk = 0; kk < 4; ++kk) {
                f32x4 a = *(const f32x4*)(qptr + kk * 32);
                f32x4 d = *(const f32x4*)(qptr + kk * 32 + 4);
                #pragma unroll
                for (int j = 0; j < 4; ++j) { qf[t][kk][j] = (__bf16)a[j]; qf[t][kk][4 + j] = (__bf16)d[j]; }
            }
        }
    };

    f32x4 oacc[4][2];     // [t][dn][r]: q = 16t+quad*4+r, d = 32wv+16dn+col
    float lsum[4];        // per-lane l partial for q = 16t+col (this wave's keys)
    float lfull[4][4];    // after finishSeg: full l for q = 16t+quad*4+r

    auto computeTile = [&](int buf, bool diag) {
        unsigned char* Tt = smem + buf * 16384;
        unsigned char* Vl = smem + 32768 + buf * 16384;

        // ---- S-phase: wave's 16 keys x all 64 q.  A = T-frag, B = qf. ----
        f32x4 sacc[4];
        #pragma unroll
        for (int t = 0; t < 4; ++t) sacc[t] = {0.f, 0.f, 0.f, 0.f};
        __builtin_amdgcn_s_setprio(1);
        #pragma unroll
        for (int kk = 0; kk < 4; ++kk) {
            int trow = wv * 16 + col;      // key = 16wv + col  (A-frag m=col)
            bf16x8 tf = *(const bf16x8*)(Tt + trow * 256 + ((kk * 64 + quad * 16) ^ ((trow & 7) << 4)));
            #pragma unroll
            for (int t = 0; t < 4; ++t)
                sacc[t] = __builtin_amdgcn_mfma_f32_16x16x32_bf16(tf, qf[t][kk], sacc[t], 0, 0, 0);
        }
        __builtin_amdgcn_s_setprio(0);

        // D[m = key = quad*4+r (+16wv)][n = q = col (+16t)]
        float p[4][4];
        #pragma unroll
        for (int t = 0; t < 4; ++t)
            #pragma unroll
            for (int r = 0; r < 4; ++r) {
                float s = sacc[t][r];
                float e = exp2f(s * EXP2C);
                p[t][r] = (s > THRESH) ? e : 1.0f;
            }
        if (diag) {
            #pragma unroll
            for (int t = 0; t < 4; ++t)
                #pragma unroll
                for (int r = 0; r < 4; ++r)
                    if (wv * 16 + quad * 4 + r > 16 * t + col) p[t][r] = 0.0f;
        }
        #pragma unroll
        for (int t = 0; t < 4; ++t)
            lsum[t] += (p[t][0] + p[t][1]) + (p[t][2] + p[t][3]);

        // P[q][key]: key axis = r => 4 contiguous bf16 = one ds_write_b64
        #pragma unroll
        for (int t = 0; t < 4; ++t) {
            int row = 16 * t + col;
            bf16x4 w = {(__bf16)p[t][0], (__bf16)p[t][1], (__bf16)p[t][2], (__bf16)p[t][3]};
            *(bf16x4*)(Pb + row * 128 + ((32 * wv + 8 * quad) ^ ((row & 7) << 4))) = w;
        }
        asm volatile("s_waitcnt lgkmcnt(0)" ::: "memory");  // P writes drained
        __builtin_amdgcn_s_barrier();                       // b2: P visible

        // ---- PV: wave's 32 d-cols x all 64 q.  A = P-frag, B = V-frag. ----
        __builtin_amdgcn_s_setprio(1);
        #pragma unroll
        for (int kb = 0; kb < 2; ++kb) {
            bf16x8 pf[4];
            #pragma unroll
            for (int t = 0; t < 4; ++t) {
                int prow = 16 * t + col;
                pf[t] = *(const bf16x8*)(Pb + prow * 128 + ((kb * 64 + quad * 16) ^ ((prow & 7) << 4)));
            }
            #pragma unroll
            for (int dn = 0; dn < 2; ++dn) {
                int vrow = 32 * wv + 16 * dn + col;
                bf16x8 vf = *(const bf16x8*)(Vl + vrow * 128 + ((kb * 64 + quad * 16) ^ ((vrow & 7) << 4)));
                #pragma unroll
                for (int t = 0; t < 4; ++t)
                    oacc[t][dn] = __builtin_amdgcn_mfma_f32_16x16x32_bf16(pf[t], vf, oacc[t][dn], 0, 0, 0);
            }
        }
        __builtin_amdgcn_s_setprio(0);
    };

    auto runSeg = [&](int jq, int k0t, int nt) {
        loadQ(jq);
        #pragma unroll
        for (int t = 0; t < 4; ++t) {
            oacc[t][0] = {0.f, 0.f, 0.f, 0.f};
            oacc[t][1] = {0.f, 0.f, 0.f, 0.f};
            lsum[t] = 0.f;
        }
        issueTile(k0t * 64, 0);
        for (int s = 0; s < nt; ++s) {
            asm volatile("s_waitcnt vmcnt(0)" ::: "memory");  // tile s landed (only its 8 loads outstanding)
            __builtin_amdgcn_s_barrier();                     // b1: all waves staged + done with other buf
            if (s + 1 < nt) issueTile((k0t + s + 1) * 64, (s + 1) & 1);  // safe after b1
            computeTile(s & 1, k0t + s == jq);                // contains b2 mid-slot
        }
    };

    // cross-wave l reduction (once per segment) through Lx[4][64] (P region)
    auto finishSeg = [&]() {
        __syncthreads();                        // last PV reads of Pb done (no b3 now)
        #pragma unroll
        for (int t = 0; t < 4; ++t) {
            float lw = lsum[t];
            lw += __shfl_xor(lw, 16);
            lw += __shfl_xor(lw, 32);          // sum over quads: wave-partial l[q=16t+col]
            if (quad == 0) Lxf[wv * 64 + 16 * t + col] = lw;
        }
        __syncthreads();
        #pragma unroll
        for (int t = 0; t < 4; ++t)
            #pragma unroll
            for (int r = 0; r < 4; ++r) {
                int q = 16 * t + quad * 4 + r;
                lfull[t][r] = (Lxf[q] + Lxf[64 + q]) + (Lxf[128 + q] + Lxf[192 + q]);
            }
        __syncthreads();                        // Lx free before next seg's P writes
    };

    auto storeO = [&](int jq) {
        float* optr = O + ((size_t)b * S_LEN + jq * 64) * D_DIM;
        #pragma unroll
        for (int t = 0; t < 4; ++t)
            #pragma unroll
            for (int r = 0; r < 4; ++r) {
                float inv = 1.0f / lfull[t][r];
                #pragma unroll
                for (int dn = 0; dn < 2; ++dn)
                    optr[(16 * t + quad * 4 + r) * D_DIM + 32 * wv + 16 * dn + col] = oacc[t][dn][r] * inv;
            }
    };

    auto storePartial = [&]() {                 // heavy prefix -> single slot pr
        __bf16* po = pO + (size_t)pr * (64 * 128);
        float*  pl = pL + (size_t)pr * 64;
        #pragma unroll
        for (int t = 0; t < 4; ++t)
            #pragma unroll
            for (int r = 0; r < 4; ++r)
                #pragma unroll
                for (int dn = 0; dn < 2; ++dn)
                    po[(16 * t + quad * 4 + r) * 128 + 32 * wv + 16 * dn + col] = (__bf16)oacc[t][dn][r];
        if (wv == 0 && col == 0) {
            #pragma unroll
            for (int t = 0; t < 4; ++t)
                #pragma unroll
                for (int r = 0; r < 4; ++r)
                    pl[16 * t + quad * 4 + r] = lfull[t][r];
        }
        __threadfence();
        __syncthreads();
        if (tid == 0)
            __hip_atomic_fetch_add(&done[pr], 1, __ATOMIC_RELEASE, __HIP_MEMORY_SCOPE_AGENT);
    };

    auto addPartial = [&]() {                   // spin for c0's prefix, then add
        if (tid == 0) {
            while (__hip_atomic_load(&done[pr], __ATOMIC_ACQUIRE, __HIP_MEMORY_SCOPE_AGENT) < 1)
                __builtin_amdgcn_s_sleep(8);
        }
        __syncthreads();
        __threadfence();
        const __bf16* po = pO + (size_t)pr * (64 * 128);
        const float*  pl = pL + (size_t)pr * 64;
        #pragma unroll
        for (int t = 0; t < 4; ++t)
            #pragma unroll
            for (int r = 0; r < 4; ++r) {
                #pragma unroll
                for (int dn = 0; dn < 2; ++dn)
                    oacc[t][dn][r] += (float)po[(16 * t + quad * 4 + r) * 128 + 32 * wv + 16 * dn + col];
                lfull[t][r] += pl[16 * t + quad * 4 + r];
            }
    };

    // ---- chunk schedule: c0 = light(L) + heavy prefix(16-L) = 16 slots;
    //      c1 = heavy suffix 17 slots incl. diagonal (arrives last; spin ~free)
    if (c == 0) {
        runSeg(pi, 0, L);                       // light, complete
        finishSeg();
        storeO(pi);
        if (L < 16) {
            runSeg(qtH, 0, 16 - L);             // heavy prefix (no diag)
            finishSeg();
            storePartial();
        }
    } else {
        runSeg(qtH, 16 - L, 17);                // heavy suffix incl. diagonal
        finishSeg();
        if (L < 16) addPartial();
        storeO(qtH);
    }
}

extern "C" void kernel_launch(void* const* d_in, const int* in_sizes, int n_in,
                              void* d_out, int out_size, void* d_ws, size_t ws_size,
                              hipStream_t stream) {
    const float* Q = (const float*)d_in[0];
    const float* T = (const float*)d_in[1];
    const float* V = (const float*)d_in[2];
    float* O = (float*)d_out;

    // ws: Vt 8MB | Tb 8MB | pO 4MB bf16 (256 pairs x 64x128) | pL 64KB | done 1KB
    unsigned char* ws = (unsigned char*)d_ws;
    __bf16* Vt = (__bf16*)ws;
    __bf16* Tb = (__bf16*)(ws + 8388608);
    __bf16* pO = (__bf16*)(ws + 16777216);
    float*  pL = (float*)(ws + 16777216 + 4194304);
    int*  done = (int*)(ws + 16777216 + 4194304 + 65536);

    prep_kernel<<<1024, 256, 0, stream>>>(V, T, Vt, Tb, done);
    fa_kernel<<<512, 256, 0, stream>>>(Q, Tb, Vt, O, pO, pL, done);
}